// Round 15
// baseline (847.871 us; speedup 1.0000x reference)
//
#include <hip/hip_runtime.h>
#include <math.h>

// CLIP surgery RecWithAttnbiasHead — round 15: 2 Q-frags x 2-way key-split.
//  - attn: r12's 2-Q-fragment density (each K/V ds_read feeds 2 MFMAs ->
//    LDS instrs/query halved; r14 showed LDS-issue ~41us floor was binding)
//    PLUS r14's key-split TLP (960 blocks ~= r11's). fp32 partials + combine.
//  - qkv/fc: gemm128; proj/fc2/head: gemm64 (both measured best).
// n=2, c=768, H=12, d=64, S=100, L=1024, N=1125, LY=3, out=512.

constexpr int Cc = 768;
constexpr int Ss = 100;
constexpr int Hh = 12;
constexpr int Ll = 1024;
constexpr int Nn = 1125;
constexpr int NB = 2;
constexpr int VTS = 1216;                    // Vt_g row stride (tokens)
constexpr float QS = 0.18033688011112042f;   // 0.125 * log2(e)
constexpr float LOG2E = 1.4426950408889634f;

typedef unsigned short u16;
typedef unsigned int u32;
typedef __attribute__((ext_vector_type(8))) short short8v;
typedef __attribute__((ext_vector_type(8))) unsigned short ushort8v;
typedef __attribute__((ext_vector_type(4))) float f32x4;
typedef __attribute__((ext_vector_type(4))) unsigned int u32x4;

__device__ inline u16 f2bf(float f) {
  unsigned u = __builtin_bit_cast(unsigned int, f);
  unsigned r = u + 0x7fffu + ((u >> 16) & 1u);
  return (u16)(r >> 16);
}
__device__ inline float bf2f(u16 v) {
  return __builtin_bit_cast(float, (unsigned int)v << 16);
}
__device__ inline unsigned cvtpk(float lo, float hi) {
  unsigned r;
  asm("v_cvt_pk_bf16_f32 %0, %1, %2" : "=v"(r) : "v"(lo), "v"(hi));
  return r;
}
__device__ inline float max3f(float a, float b, float c) {
  float r;
  asm("v_max3_f32 %0, %1, %2, %3" : "=v"(r) : "v"(a), "v"(b), "v"(c));
  return r;
}

// XOR-swizzled flat index into a [rows][64] bf16 LDS tile (16B-chunk swizzle).
__device__ inline int swz(int row, int col) {
  return (row << 6) + ((((col >> 3) ^ (row & 7)) << 3) | (col & 7));
}

// ---------------- assemble token streams ----------------
__global__ __launch_bounds__(256) void assemble_kernel(
    const float* __restrict__ cls, const float* __restrict__ pix,
    const float* __restrict__ sur, float* __restrict__ xo, float* __restrict__ xs) {
  int idx = blockIdx.x * 256 + (int)threadIdx.x;
  int total = NB * Nn * Cc;
  if (idx >= total) return;
  int ch = idx % Cc;
  int t  = (idx / Cc) % Nn;
  int b  = idx / (Cc * Nn);
  float vo, vs;
  if (t <= Ss) vo = cls[b * Cc + ch];
  else         vo = pix[(size_t)b * Cc * Ll + (size_t)ch * Ll + (t - Ss - 1)];
  if (t < Ss)  vs = sur[b * Cc + ch];
  else         vs = sur[(size_t)(t - Ss) * NB * Cc + b * Cc + ch];
  xo[idx] = vo;
  xs[idx] = vs;
}

// ---------------- merged fp32 -> bf16 weight convert ----------------
constexpr int CN0 = 3 * 2304 * 768;
constexpr int CN1 = 3 * 768 * 768;
constexpr int CN2 = 3 * 3072 * 768;
constexpr int CN3 = 3 * 768 * 3072;
__global__ __launch_bounds__(256) void cvt4_kernel(
    const float* __restrict__ s0, const float* __restrict__ s1,
    const float* __restrict__ s2, const float* __restrict__ s3,
    u16* __restrict__ dst) {
  int i4 = (blockIdx.x * 256 + (int)threadIdx.x) * 4;
  if (i4 >= CN0 + CN1 + CN2 + CN3) return;
  const float* src; int off;
  if (i4 < CN0)             { src = s0; off = i4; }
  else if (i4 < CN0 + CN1)  { src = s1; off = i4 - CN0; }
  else if (i4 < CN0 + CN1 + CN2) { src = s2; off = i4 - CN0 - CN1; }
  else                      { src = s3; off = i4 - CN0 - CN1 - CN2; }
  float4 v = *(const float4*)(src + off);
  *(ushort4*)(dst + i4) = make_ushort4(f2bf(v.x), f2bf(v.y), f2bf(v.z), f2bf(v.w));
}

// transpose proj_out [768][512] fp32 -> [512][768] bf16
__global__ __launch_bounds__(256) void transpose_po_kernel(
    const float* __restrict__ in, u16* __restrict__ out) {
  int id = blockIdx.x * 256 + (int)threadIdx.x;
  if (id >= 512 * 768) return;
  int nidx = id / 768, k = id - nidx * 768;
  out[id] = f2bf(in[(size_t)k * 512 + nidx]);
}

// ---------------- per-layer V transpose: qkv V -> Vt_g[bh][d][tok VTS] ----
__global__ __launch_bounds__(256) void vtrans_kernel(
    const u16* __restrict__ qkv, u16* __restrict__ vtg) {
  __shared__ u16 tile[64][72];
  int tt = blockIdx.x;   // 0..18 token tiles (tile 18 = zero pad)
  int bh = blockIdx.y;   // 0..23
  int b = bh / Hh, h = bh - b * Hh;
  int tid = (int)threadIdx.x;
  {
    int tl = tid >> 2, c0 = (tid & 3) << 4;
    int tok = tt * 64 + tl;
    int tokc = tok > 1124 ? 1124 : tok;
    const u16* src = qkv + ((size_t)(b * Nn + tokc)) * 2304 + 2 * Cc + h * 64 + c0;
    ushort8v v0 = *(const ushort8v*)src;
    ushort8v v1 = *(const ushort8v*)(src + 8);
    if (tok > 1124) { v0 = (ushort8v)0; v1 = (ushort8v)0; }
    *(ushort8v*)&tile[tl][c0] = v0;
    *(ushort8v*)&tile[tl][c0 + 8] = v1;
  }
  __syncthreads();
  {
    int d = tid >> 2, t0 = (tid & 3) << 4;
    ushort8v o0, o1;
#pragma unroll
    for (int j = 0; j < 8; ++j) { o0[j] = tile[t0 + j][d]; o1[j] = tile[t0 + 8 + j][d]; }
    size_t orow = ((size_t)bh * 64 + d) * VTS + tt * 64 + t0;
    *(ushort8v*)&vtg[orow] = o0;
    *(ushort8v*)&vtg[orow + 8] = o1;
  }
}

// ---------------- layer norm (fp32 in, bf16 out, row gather) ----------------
__global__ __launch_bounds__(256) void ln_kernel(
    const float* __restrict__ X, const float* __restrict__ w, const float* __restrict__ b,
    u16* __restrict__ Y, int rows_per_b, int row_off) {
  int r = blockIdx.x;
  int bb = r / rows_per_b;
  int i  = r % rows_per_b;
  const float* x = X + ((size_t)bb * Nn + row_off + i) * Cc;
  u16* y = Y + (size_t)r * Cc;
  int tid = (int)threadIdx.x;
  float v0 = x[tid], v1 = x[tid + 256], v2 = x[tid + 512];
  float s = v0 + v1 + v2;
  __shared__ float sbuf[4];
  for (int off = 32; off; off >>= 1) s += __shfl_xor(s, off);
  if ((tid & 63) == 0) sbuf[tid >> 6] = s;
  __syncthreads();
  float mean = (sbuf[0] + sbuf[1] + sbuf[2] + sbuf[3]) * (1.0f / Cc);
  float d0 = v0 - mean, d1 = v1 - mean, d2 = v2 - mean;
  float q = d0 * d0 + d1 * d1 + d2 * d2;
  __syncthreads();
  for (int off = 32; off; off >>= 1) q += __shfl_xor(q, off);
  if ((tid & 63) == 0) sbuf[tid >> 6] = q;
  __syncthreads();
  float var = (sbuf[0] + sbuf[1] + sbuf[2] + sbuf[3]) * (1.0f / Cc);
  float inv = rsqrtf(var + 1e-5f);
  y[tid]       = f2bf(d0 * inv * w[tid]       + b[tid]);
  y[tid + 256] = f2bf(d1 * inv * w[tid + 256] + b[tid + 256]);
  y[tid + 512] = f2bf(d2 * inv * w[tid + 512] + b[tid + 512]);
}

// ---------------- bf16 MFMA GEMM, 128x128 tile (qkv / fc) ----------------
__global__ __launch_bounds__(256) void gemm128_kernel(
    const u16* __restrict__ A, const u16* __restrict__ B,
    const float* __restrict__ bias, u16* __restrict__ outb,
    int M, int N, int K, int act) {
  __shared__ __align__(16) u16 Als[128 * 64];
  __shared__ __align__(16) u16 Bls[128 * 64];
  int tid = (int)threadIdx.x;
  int wave = tid >> 6, lane = tid & 63, g = lane >> 4, li = lane & 15;
  int wm = wave >> 1, wn = wave & 1;
  int row0 = blockIdx.y * 128, col0 = blockIdx.x * 128;

  const u16* aptr[4]; const u16* bptr[4]; int dsti[4];
#pragma unroll
  for (int j = 0; j < 4; ++j) {
    int c = tid + j * 256;
    int r = c >> 3, c8 = c & 7;
    dsti[j] = (r << 6) + ((c8 ^ (r & 7)) << 3);
    int ra = row0 + r; if (ra > M - 1) ra = M - 1;
    aptr[j] = A + (size_t)ra * K + (c8 << 3);
    bptr[j] = B + (size_t)(col0 + r) * K + (c8 << 3);
  }

  f32x4 acc[4][4];
#pragma unroll
  for (int mi = 0; mi < 4; ++mi)
#pragma unroll
    for (int ni = 0; ni < 4; ++ni) acc[mi][ni] = (f32x4){0.f, 0.f, 0.f, 0.f};

  for (int k0 = 0; k0 < K; k0 += 64) {
    ushort8v ta[4], tb[4];
#pragma unroll
    for (int j = 0; j < 4; ++j) {
      ta[j] = *(const ushort8v*)(aptr[j] + k0);
      tb[j] = *(const ushort8v*)(bptr[j] + k0);
    }
    __syncthreads();
#pragma unroll
    for (int j = 0; j < 4; ++j) {
      *(ushort8v*)&Als[dsti[j]] = ta[j];
      *(ushort8v*)&Bls[dsti[j]] = tb[j];
    }
    __syncthreads();
#pragma unroll
    for (int kc = 0; kc < 2; ++kc) {
      short8v af[4], bfr[4];
#pragma unroll
      for (int mi = 0; mi < 4; ++mi) {
        int rr = wm * 64 + mi * 16 + li;
        af[mi] = *(const short8v*)&Als[(rr << 6) + (((kc * 4 + g) ^ (rr & 7)) << 3)];
      }
#pragma unroll
      for (int ni = 0; ni < 4; ++ni) {
        int rb = wn * 64 + ni * 16 + li;
        bfr[ni] = *(const short8v*)&Bls[(rb << 6) + (((kc * 4 + g) ^ (rb & 7)) << 3)];
      }
      __builtin_amdgcn_s_setprio(1);
#pragma unroll
      for (int mi = 0; mi < 4; ++mi)
#pragma unroll
        for (int ni = 0; ni < 4; ++ni)
          acc[mi][ni] = __builtin_amdgcn_mfma_f32_16x16x32_bf16(af[mi], bfr[ni], acc[mi][ni], 0, 0, 0);
      __builtin_amdgcn_s_setprio(0);
    }
  }

#pragma unroll
  for (int mi = 0; mi < 4; ++mi) {
#pragma unroll
    for (int r = 0; r < 4; ++r) {
      int m = row0 + wm * 64 + mi * 16 + g * 4 + r;
      if (m >= M) continue;
#pragma unroll
      for (int ni = 0; ni < 4; ++ni) {
        int n = col0 + wn * 64 + ni * 16 + li;
        float v = acc[mi][ni][r];
        if (bias) v += bias[n];
        if (act)  v = v / (1.0f + __expf(-1.702f * v));
        outb[(size_t)m * N + n] = f2bf(v);
      }
    }
  }
}

// ---------------- bf16 MFMA GEMM, 64x128 tile (proj/fc2/head) ---------------
__global__ __launch_bounds__(256) void gemm64_kernel(
    const u16* __restrict__ A0, const u16* __restrict__ A1,
    const u16* __restrict__ B, const float* __restrict__ bias,
    const float* __restrict__ res0, const float* __restrict__ res1,
    float* __restrict__ outf0, float* __restrict__ outf1,
    u16* __restrict__ outb0, u16* __restrict__ outb1,
    int M, int N, int K, int act) {
  __shared__ __align__(16) u16 Als[64 * 64];
  __shared__ __align__(16) u16 Bls[128 * 64];
  int zz = blockIdx.z;
  const u16* A = zz ? A1 : A0;
  const float* res = zz ? res1 : res0;
  float* outf = zz ? outf1 : outf0;
  u16* outb = zz ? outb1 : outb0;
  int tid = (int)threadIdx.x;
  int wave = tid >> 6, lane = tid & 63, g = lane >> 4, li = lane & 15;
  int row0 = blockIdx.y * 64, col0 = blockIdx.x * 128;

  const u16* aptr[2]; int dA[2];
#pragma unroll
  for (int j = 0; j < 2; ++j) {
    int ca = tid + j * 256;
    int r = ca >> 3, c8 = ca & 7;
    dA[j] = (r << 6) + ((c8 ^ (r & 7)) << 3);
    int ra = row0 + r; if (ra > M - 1) ra = M - 1;
    aptr[j] = A + (size_t)ra * K + (c8 << 3);
  }
  const u16* bptr[4]; int dB[4];
#pragma unroll
  for (int j = 0; j < 4; ++j) {
    int cb = tid + j * 256;
    int r = cb >> 3, c8 = cb & 7;
    dB[j] = (r << 6) + ((c8 ^ (r & 7)) << 3);
    bptr[j] = B + (size_t)(col0 + r) * K + (c8 << 3);
  }

  f32x4 acc[4][2];
#pragma unroll
  for (int mi = 0; mi < 4; ++mi)
#pragma unroll
    for (int ni = 0; ni < 2; ++ni) acc[mi][ni] = (f32x4){0.f, 0.f, 0.f, 0.f};

  for (int k0 = 0; k0 < K; k0 += 64) {
    ushort8v ta[2], tb[4];
#pragma unroll
    for (int j = 0; j < 2; ++j) ta[j] = *(const ushort8v*)(aptr[j] + k0);
#pragma unroll
    for (int j = 0; j < 4; ++j) tb[j] = *(const ushort8v*)(bptr[j] + k0);
    __syncthreads();
#pragma unroll
    for (int j = 0; j < 2; ++j) *(ushort8v*)&Als[dA[j]] = ta[j];
#pragma unroll
    for (int j = 0; j < 4; ++j) *(ushort8v*)&Bls[dB[j]] = tb[j];
    __syncthreads();
#pragma unroll
    for (int kc = 0; kc < 2; ++kc) {
      short8v af[4], bfr[2];
#pragma unroll
      for (int mi = 0; mi < 4; ++mi) {
        int rr = mi * 16 + li;
        af[mi] = *(const short8v*)&Als[(rr << 6) + (((kc * 4 + g) ^ (rr & 7)) << 3)];
      }
#pragma unroll
      for (int ni = 0; ni < 2; ++ni) {
        int rb = wave * 32 + ni * 16 + li;
        bfr[ni] = *(const short8v*)&Bls[(rb << 6) + (((kc * 4 + g) ^ (rb & 7)) << 3)];
      }
      __builtin_amdgcn_s_setprio(1);
#pragma unroll
      for (int mi = 0; mi < 4; ++mi)
#pragma unroll
        for (int ni = 0; ni < 2; ++ni)
          acc[mi][ni] = __builtin_amdgcn_mfma_f32_16x16x32_bf16(af[mi], bfr[ni], acc[mi][ni], 0, 0, 0);
      __builtin_amdgcn_s_setprio(0);
    }
  }

#pragma unroll
  for (int mi = 0; mi < 4; ++mi) {
#pragma unroll
    for (int r = 0; r < 4; ++r) {
      int m = row0 + mi * 16 + g * 4 + r;
      if (m >= M) continue;
#pragma unroll
      for (int ni = 0; ni < 2; ++ni) {
        int n = col0 + wave * 32 + ni * 16 + li;
        float v = acc[mi][ni][r];
        if (bias) v += bias[n];
        if (act)  v = v / (1.0f + __expf(-1.702f * v));
        if (res)  v += res[(size_t)m * N + n];
        if (outf) outf[(size_t)m * N + n] = v;
        else      outb[(size_t)m * N + n] = f2bf(v);
      }
    }
  }
}

// ---------------- attn: 2 Q-frags x 2-way key-split -------------------------
// Grid 960 = 8 XCD chunks x 120. virt -> gidh = virt/10, qt = virt%10;
// half = gidh&1, gid = gidh>>1; z = gid/24, bh = gid%24.
// Per wave: 32 queries in 2 frags (q = qbase + f*16 + li); each K/V ds_read
// feeds 2 MFMAs. K rows at LDS row rho(k); Vt key-identity.
// pixel (qt<9): qbase = 100+128qt+wave*32, 17 tiles t0 = 96+64kt.
// sos (qt=9): qbase = wave*32, 19 tiles (kt<=1 diag: t0=64kt, key==qtok_f;
// else t0 = 64(kt-1)+32, +abias*log2e in ORI). half0: kt<9, half1: kt>=9.
// Emits fp32 unnormalized O-partials + (m,l) (log2); ALWAYS-rescale.
__global__ __launch_bounds__(256) void attn_kernel(
    const u16* __restrict__ qkv, const u16* __restrict__ vtg,
    const float* __restrict__ abias,
    float* __restrict__ opart, float* __restrict__ mlp) {
  __shared__ __align__(16) u16 Klds[64 * 64];
  __shared__ __align__(16) u16 Vt[64 * 64];      // [d][key] swizzled
  int id = (int)blockIdx.x;
  int virt = (id & 7) * 120 + (id >> 3);   // 960 = 8*120, bijective
  int gidh = virt / 10;
  int qt   = virt - gidh * 10;
  int half = gidh & 1;
  int gid  = gidh >> 1;
  int z    = gid / 24;                      // pass: 0=ORI, 1=SUR
  int bh   = gid - z * 24;
  int b = bh / Hh, h = bh - b * Hh;
  int tid = (int)threadIdx.x;
  int wave = tid >> 6, lane = tid & 63, g = lane >> 4, li = lane & 15;
  bool sosq = (qt == 9);

  int qbase = sosq ? wave * 32 : 100 + qt * 128 + wave * 32;
  int qcap = sosq ? 99 : 1124;
  int qtokf[2];
  qtokf[0] = qbase + li;       if (qtokf[0] > qcap) qtokf[0] = qcap;
  qtokf[1] = qbase + 16 + li;  if (qtokf[1] > qcap) qtokf[1] = qcap;
  int qoff = z ? 2 * Cc + h * 64 : h * 64;
  int koff = z ? 2 * Cc + h * 64 : Cc + h * 64;

  // B-fragments: lane holds q rows qtokf[0/1], pre-scaled by 0.125*log2e
  short8v qf[2][2];
#pragma unroll
  for (int f = 0; f < 2; ++f) {
    const u16* qp = qkv + ((size_t)b * Nn + qtokf[f]) * 2304 + qoff;
#pragma unroll
    for (int kc = 0; kc < 2; ++kc) {
      ushort8v a = *(const ushort8v*)(qp + kc * 32 + g * 8);
      u32x4 w;
#pragma unroll
      for (int jj = 0; jj < 4; ++jj)
        w[jj] = cvtpk(bf2f(a[2 * jj]) * QS, bf2f(a[2 * jj + 1]) * QS);
      qf[f][kc] = __builtin_bit_cast(short8v, w);
    }
  }

  int skey = tid >> 2;           // K: key row staged; Vt: d row staged
  int sd0  = (tid & 3) << 4;
  int prow = 16 * (2 * (skey >> 5) + ((skey >> 2) & 1)) + 4 * ((skey >> 3) & 3) + (skey & 3);
  int kK0 = swz(prow, sd0), kK1 = swz(prow, sd0 + 8);
  int vI0 = swz(skey, sd0), vI1 = swz(skey, sd0 + 8);
  const u16* kbase = qkv + (size_t)b * Nn * 2304 + koff + sd0;
  const u16* vbase = vtg + ((size_t)bh * 64 + skey) * VTS + sd0;

  const int KOFF[4] = {0, 4, 32, 36};   // within-tile key base per nt (+8g+r)

  f32x4 oacc[2][4];
#pragma unroll
  for (int f = 0; f < 2; ++f)
#pragma unroll
    for (int dt = 0; dt < 4; ++dt) oacc[f][dt] = (f32x4){0.f, 0.f, 0.f, 0.f};
  float mrow[2] = {-1e30f, -1e30f}, lrow[2] = {0.f, 0.f};

  int NT = sosq ? 19 : 17;
  int kt0 = half * 9;
  int kt1 = half ? NT : 9;
  for (int kt = kt0; kt < kt1; ++kt) {
    int t0 = sosq ? (kt <= 1 ? 64 * kt : 64 * (kt - 1) + 32) : 96 + 64 * kt;
    __syncthreads();
    {
      int ktok = t0 + skey; if (ktok > 1124) ktok = 1124;
      const u16* kp = kbase + (size_t)ktok * 2304;
      ushort8v k0v = *(const ushort8v*)kp;
      ushort8v k1v = *(const ushort8v*)(kp + 8);
      const u16* vp = vbase + t0;
      ushort8v v0 = *(const ushort8v*)vp;
      ushort8v v1 = *(const ushort8v*)(vp + 8);
      *(ushort8v*)&Klds[kK0] = k0v;
      *(ushort8v*)&Klds[kK1] = k1v;
      *(ushort8v*)&Vt[vI0] = v0;
      *(ushort8v*)&Vt[vI1] = v1;
    }
    __syncthreads();

    // S^T = K Q^T, both frags share each kb read
    f32x4 sacc[2][4];
#pragma unroll
    for (int f = 0; f < 2; ++f)
#pragma unroll
      for (int nt = 0; nt < 4; ++nt) sacc[f][nt] = (f32x4){0.f, 0.f, 0.f, 0.f};
    __builtin_amdgcn_s_setprio(1);
#pragma unroll
    for (int kc = 0; kc < 2; ++kc) {
#pragma unroll
      for (int nt = 0; nt < 4; ++nt) {
        short8v kb = *(const short8v*)&Klds[swz(nt * 16 + li, kc * 32 + g * 8)];
        sacc[0][nt] = __builtin_amdgcn_mfma_f32_16x16x32_bf16(kb, qf[0][kc], sacc[0][nt], 0, 0, 0);
        sacc[1][nt] = __builtin_amdgcn_mfma_f32_16x16x32_bf16(kb, qf[1][kc], sacc[1][nt], 0, 0, 0);
      }
    }
    __builtin_amdgcn_s_setprio(0);

    // masking / bias; lane's (f,nt,r) is key t0 + KOFF[nt] + 8g + r
    int tg = t0 + 8 * g;
    if (!sosq) {
      if (kt == 0) {
#pragma unroll
        for (int f = 0; f < 2; ++f)
#pragma unroll
          for (int nt = 0; nt < 4; ++nt)
#pragma unroll
            for (int r = 0; r < 4; ++r)
              if (tg + KOFF[nt] + r < 100) sacc[f][nt][r] = -1e30f;
      } else if (kt == 16) {
#pragma unroll
        for (int f = 0; f < 2; ++f)
#pragma unroll
          for (int nt = 0; nt < 4; ++nt)
#pragma unroll
            for (int r = 0; r < 4; ++r)
              if (tg + KOFF[nt] + r > 1124) sacc[f][nt][r] = -1e30f;
      }
    } else {
      if (kt <= 1) {
#pragma unroll
        for (int f = 0; f < 2; ++f)
#pragma unroll
          for (int nt = 0; nt < 4; ++nt)
#pragma unroll
            for (int r = 0; r < 4; ++r)
              if (tg + KOFF[nt] + r != qtokf[f]) sacc[f][nt][r] = -1e30f;
      } else if (z == 0) {
#pragma unroll
        for (int f = 0; f < 2; ++f) {
          const float* bp = abias + ((size_t)b * Ss + qtokf[f]) * Ll;
#pragma unroll
          for (int nt = 0; nt < 4; ++nt)
#pragma unroll
            for (int r = 0; r < 4; ++r) {
              int tok = tg + KOFF[nt] + r;
              int bi = tok - 101; bi = bi < 0 ? 0 : bi; bi = bi > 1023 ? 1023 : bi;
              float bv = bp[bi];
              bool bad = (tok < 101) | (tok > 1124);
              sacc[f][nt][r] = bad ? -1e30f : fmaf(bv, LOG2E, sacc[f][nt][r]);
            }
        }
      } else {
#pragma unroll
        for (int f = 0; f < 2; ++f)
#pragma unroll
          for (int nt = 0; nt < 4; ++nt)
#pragma unroll
            for (int r = 0; r < 4; ++r) {
              int tok = tg + KOFF[nt] + r;
              if ((tok < 101) | (tok > 1124)) sacc[f][nt][r] = -1e30f;
            }
      }
    }

    // online softmax per frag (log2 domain), ALWAYS-rescale
#pragma unroll
    for (int f = 0; f < 2; ++f) {
      float rmax = max3f(sacc[f][0][0], sacc[f][0][1], sacc[f][0][2]);
      rmax = max3f(rmax, sacc[f][0][3], sacc[f][1][0]);
      rmax = max3f(rmax, sacc[f][1][1], sacc[f][1][2]);
      rmax = max3f(rmax, sacc[f][1][3], sacc[f][2][0]);
      rmax = max3f(rmax, sacc[f][2][1], sacc[f][2][2]);
      rmax = max3f(rmax, sacc[f][2][3], sacc[f][3][0]);
      rmax = max3f(rmax, sacc[f][3][1], sacc[f][3][2]);
      rmax = fmaxf(rmax, sacc[f][3][3]);
      rmax = fmaxf(rmax, __shfl_xor(rmax, 16));
      rmax = fmaxf(rmax, __shfl_xor(rmax, 32));
      float mnew = fmaxf(mrow[f], rmax);
      float fac = __builtin_amdgcn_exp2f(mrow[f] - mnew);
      mrow[f] = mnew;
      float psum = 0.f;
#pragma unroll
      for (int nt = 0; nt < 4; ++nt)
#pragma unroll
        for (int r = 0; r < 4; ++r) {
          float e = __builtin_amdgcn_exp2f(sacc[f][nt][r] - mnew);
          sacc[f][nt][r] = e;
          psum += e;
        }
      psum += __shfl_xor(psum, 16);
      psum += __shfl_xor(psum, 32);
      lrow[f] = lrow[f] * fac + psum;
#pragma unroll
      for (int dt = 0; dt < 4; ++dt) oacc[f][dt] *= fac;
    }

    // O^T += V^T P^T : both frags share each va read
    __builtin_amdgcn_s_setprio(1);
#pragma unroll
    for (int kcp = 0; kcp < 2; ++kcp) {
      short8v pb[2];
#pragma unroll
      for (int f = 0; f < 2; ++f) {
        u32x4 pwv;
#pragma unroll
        for (int w = 0; w < 4; ++w) {
          int nt = 2 * kcp + (w >> 1);
          int r0 = (w & 1) * 2;
          pwv[w] = cvtpk(sacc[f][nt][r0], sacc[f][nt][r0 + 1]);
        }
        pb[f] = __builtin_bit_cast(short8v, pwv);
      }
#pragma unroll
      for (int dt = 0; dt < 4; ++dt) {
        short8v va = *(const short8v*)&Vt[swz(dt * 16 + li, kcp * 32 + g * 8)];
        oacc[0][dt] = __builtin_amdgcn_mfma_f32_16x16x32_bf16(va, pb[0], oacc[0][dt], 0, 0, 0);
        oacc[1][dt] = __builtin_amdgcn_mfma_f32_16x16x32_bf16(va, pb[1], oacc[1][dt], 0, 0, 0);
      }
    }
    __builtin_amdgcn_s_setprio(0);
  }

  // epilogue: fp32 partials per frag + (m,l) from g==0 lane
  int hp = half * 2 + z;
#pragma unroll
  for (int f = 0; f < 2; ++f) {
    int tok = qbase + f * 16 + li;
    if (tok > qcap) continue;
    float* op = opart + ((size_t)hp * NB * Nn + (size_t)b * Nn + tok) * Cc + h * 64 + g * 4;
#pragma unroll
    for (int dt = 0; dt < 4; ++dt)
      *(float4*)(op + dt * 16) = make_float4(oacc[f][dt][0], oacc[f][dt][1], oacc[f][dt][2], oacc[f][dt][3]);
    if (g == 0) {
      size_t mb = (((size_t)hp * 24 + bh) * Nn + tok) * 2;
      mlp[mb] = mrow[f];
      mlp[mb + 1] = lrow[f];
    }
  }
}

// ---------------- combine key-halves (log2-domain flash merge) --------------
__global__ __launch_bounds__(256) void attn_combine_kernel(
    const float* __restrict__ opart, const float* __restrict__ mlp,
    u16* __restrict__ ao, u16* __restrict__ as_) {
  int blk = blockIdx.x;            // pass*(NB*Nn) + row
  int pass = blk / (NB * Nn);
  int row = blk - pass * (NB * Nn);
  int b = row / Nn, i = row - b * Nn;
  u16* outp = pass ? as_ : ao;
  int tid = (int)threadIdx.x;
#pragma unroll
  for (int e = 0; e < 3; ++e) {
    int c = tid + e * 256;
    int h = c >> 6;
    int bh = b * Hh + h;
    size_t m0i = (((size_t)(0 * 2 + pass) * 24 + bh) * Nn + i) * 2;
    size_t m1i = (((size_t)(1 * 2 + pass) * 24 + bh) * Nn + i) * 2;
    float m0 = mlp[m0i], l0 = mlp[m0i + 1];
    float m1 = mlp[m1i], l1 = mlp[m1i + 1];
    float M = fmaxf(m0, m1);
    float w0 = __builtin_amdgcn_exp2f(m0 - M);
    float w1 = __builtin_amdgcn_exp2f(m1 - M);
    float L = l0 * w0 + l1 * w1;
    float v0 = opart[((size_t)(0 * 2 + pass) * NB * Nn + row) * Cc + c];
    float v1 = opart[((size_t)(1 * 2 + pass) * NB * Nn + row) * Cc + c];
    outp[(size_t)row * Cc + c] = f2bf((v0 * w0 + v1 * w1) / L);
  }
}

// ---------------- l2norm heads ----------------
__global__ __launch_bounds__(256) void l2norm_sos_kernel(
    const float* __restrict__ Xp, float* __restrict__ out) {
  int r = blockIdx.x;
  int tid = (int)threadIdx.x;
  const float* x = Xp + (size_t)r * 512;
  float v0 = x[tid], v1 = x[tid + 256];
  float s = v0 * v0 + v1 * v1;
  __shared__ float sbuf[4];
  for (int off = 32; off; off >>= 1) s += __shfl_xor(s, off);
  if ((tid & 63) == 0) sbuf[tid >> 6] = s;
  __syncthreads();
  float tot = sbuf[0] + sbuf[1] + sbuf[2] + sbuf[3];
  float inv = 1.0f / fmaxf(sqrtf(tot), 1e-12f);
  out[(size_t)r * 512 + tid]       = v0 * inv;
  out[(size_t)r * 512 + tid + 256] = v1 * inv;
}

__global__ __launch_bounds__(256) void l2norm_img_kernel(
    const float* __restrict__ Xp, float* __restrict__ out) {
  int r = blockIdx.x;           // b*1025 + ti
  int b = r / 1025, ti = r % 1025;
  int tid = (int)threadIdx.x;
  const float* x = Xp + (size_t)r * 512;
  float v0 = x[tid], v1 = x[tid + 256];
  float s = v0 * v0 + v1 * v1;
  __shared__ float sbuf[4];
  for (int off = 32; off; off >>= 1) s += __shfl_xor(s, off);
  if ((tid & 63) == 0) sbuf[tid >> 6] = s;
  __syncthreads();
  float tot = sbuf[0] + sbuf[1] + sbuf[2] + sbuf[3];
  if (ti == 0) return;          // first surgery row (token S) is discarded
  float inv = 1.0f / fmaxf(sqrtf(tot), 1e-12f);
  float* o = out + (size_t)b * 512 * 1024 + (ti - 1);
  o[(size_t)tid * 1024]         = v0 * inv;
  o[(size_t)(tid + 256) * 1024] = v1 * inv;
}

extern "C" void kernel_launch(void* const* d_in, const int* in_sizes, int n_in,
                              void* d_out, int out_size, void* d_ws, size_t ws_size,
                              hipStream_t stream) {
  const float* cls      = (const float*)d_in[0];
  const float* pix      = (const float*)d_in[1];
  const float* sur      = (const float*)d_in[2];
  const float* abias    = (const float*)d_in[3];
  const float* qkv_w    = (const float*)d_in[4];
  const float* qkv_b    = (const float*)d_in[5];
  const float* proj_w   = (const float*)d_in[6];
  const float* proj_b   = (const float*)d_in[7];
  const float* ln1_w    = (const float*)d_in[8];
  const float* ln1_b    = (const float*)d_in[9];
  const float* ln2_w    = (const float*)d_in[10];
  const float* ln2_b    = (const float*)d_in[11];
  const float* fc_w     = (const float*)d_in[12];
  const float* fc_b     = (const float*)d_in[13];
  const float* fc2_w    = (const float*)d_in[14];
  const float* fc2_b    = (const float*)d_in[15];
  const float* lnp_w    = (const float*)d_in[16];
  const float* lnp_b    = (const float*)d_in[17];
  const float* proj_o   = (const float*)d_in[18];
  float* out = (float*)d_out;

  const size_t SZ = (size_t)NB * Nn * Cc;        // 1,728,000
  float* xo    = (float*)d_ws;
  float* xs    = xo + SZ;
  float* opart = xs + SZ;                         // 4*2250*768 f32
  float* mlp   = opart + (size_t)4 * 2250 * 768;  // 4*24*1125*2 f32
  float* head_pj = opart;                         // reused at head phase
  u16* tln_bf = (u16*)(mlp + (size_t)4 * 24 * 1125 * 2);
  u16* act_bf = tln_bf + (size_t)2250 * 768;      // 2250*3072
  u16* ao_bf  = act_bf + (size_t)2250 * 3072;     // 2250*768
  u16* as_bf  = ao_bf + (size_t)2250 * 768;       // 2250*768
  u16* wq_bf  = as_bf + (size_t)2250 * 768;       // 3*2304*768
  u16* wp_bf  = wq_bf + (size_t)CN0;              // 3*768*768
  u16* wf_bf  = wp_bf + (size_t)CN1;              // 3*3072*768
  u16* w2_bf  = wf_bf + (size_t)CN2;              // 3*768*3072
  u16* wo_bf  = w2_bf + (size_t)CN3;              // 512*768
  u16* vtg    = wo_bf + (size_t)512 * 768;        // 24*64*VTS

  assemble_kernel<<<6750, 256, 0, stream>>>(cls, pix, sur, xo, xs);
  cvt4_kernel<<<20736, 256, 0, stream>>>(qkv_w, proj_w, fc_w, fc2_w, wq_bf);
  transpose_po_kernel<<<1536, 256, 0, stream>>>(proj_o, wo_bf);

  for (int l = 0; l < 3; ++l) {
    ln_kernel<<<2250, 256, 0, stream>>>(xo, ln1_w + l * 768, ln1_b + l * 768, tln_bf, Nn, 0);
    gemm128_kernel<<<dim3(18, 18), 256, 0, stream>>>(
        tln_bf, wq_bf + (size_t)l * 2304 * 768, qkv_b + l * 2304,
        act_bf, 2250, 2304, 768, 0);
    vtrans_kernel<<<dim3(19, 24), 256, 0, stream>>>(act_bf, vtg);
    attn_kernel<<<960, 256, 0, stream>>>(act_bf, vtg, abias, opart, mlp);
    attn_combine_kernel<<<4500, 256, 0, stream>>>(opart, mlp, ao_bf, as_bf);
    gemm64_kernel<<<dim3(6, 36, 2), 256, 0, stream>>>(
        ao_bf, as_bf, wp_bf + (size_t)l * 768 * 768, proj_b + l * 768,
        xo, xs, xo, xs, nullptr, nullptr, 2250, 768, 768, 0);
    ln_kernel<<<2250, 256, 0, stream>>>(xo, ln2_w + l * 768, ln2_b + l * 768, tln_bf, Nn, 0);
    gemm128_kernel<<<dim3(24, 18), 256, 0, stream>>>(
        tln_bf, wf_bf + (size_t)l * 3072 * 768, fc_b + l * 3072,
        act_bf, 2250, 3072, 768, 1);
    gemm64_kernel<<<dim3(6, 36, 1), 256, 0, stream>>>(
        act_bf, act_bf, w2_bf + (size_t)l * 768 * 3072, fc2_b + l * 768,
        xo, xo, xo, xo, nullptr, nullptr, 2250, 768, 3072, 0);
  }

  // heads
  ln_kernel<<<200, 256, 0, stream>>>(xo, lnp_w, lnp_b, tln_bf, 100, 0);
  ln_kernel<<<2050, 256, 0, stream>>>(xs, lnp_w, lnp_b, tln_bf + 200 * 768, 1025, 100);
  gemm64_kernel<<<dim3(4, 36, 1), 256, 0, stream>>>(
      tln_bf, tln_bf, wo_bf, nullptr,
      nullptr, nullptr, head_pj, head_pj, nullptr, nullptr, 2250, 512, 768, 0);
  l2norm_sos_kernel<<<200, 256, 0, stream>>>(head_pj, out);
  l2norm_img_kernel<<<2050, 256, 0, stream>>>(head_pj + 200 * 512, out + 102400);
}

// Round 16
// 753.149 us; speedup vs baseline: 1.1258x; 1.1258x over previous
//
#include <hip/hip_runtime.h>
#include <math.h>

// CLIP surgery RecWithAttnbiasHead — round 16: REVERT to round-14 (measured
// best, 753.9us). r15's 2-Q-frag variant cost 104 VGPR -> occupancy 8.4% and
// regressed; attn's ~77us is the structure floor (TLP/density/dbuf all probed).
//  - attn: 2-way key-split (1824 blocks), fp32 partials + combine.
//  - qkv/fc: gemm128; proj/fc2/head: gemm64.
// n=2, c=768, H=12, d=64, S=100, L=1024, N=1125, LY=3, out=512.

constexpr int Cc = 768;
constexpr int Ss = 100;
constexpr int Hh = 12;
constexpr int Ll = 1024;
constexpr int Nn = 1125;
constexpr int NB = 2;
constexpr int VTS = 1216;                    // Vt_g row stride (tokens)
constexpr float QS = 0.18033688011112042f;   // 0.125 * log2(e)
constexpr float LOG2E = 1.4426950408889634f;

typedef unsigned short u16;
typedef unsigned int u32;
typedef __attribute__((ext_vector_type(8))) short short8v;
typedef __attribute__((ext_vector_type(8))) unsigned short ushort8v;
typedef __attribute__((ext_vector_type(4))) float f32x4;
typedef __attribute__((ext_vector_type(4))) unsigned int u32x4;

__device__ inline u16 f2bf(float f) {
  unsigned u = __builtin_bit_cast(unsigned int, f);
  unsigned r = u + 0x7fffu + ((u >> 16) & 1u);
  return (u16)(r >> 16);
}
__device__ inline float bf2f(u16 v) {
  return __builtin_bit_cast(float, (unsigned int)v << 16);
}
__device__ inline unsigned cvtpk(float lo, float hi) {
  unsigned r;
  asm("v_cvt_pk_bf16_f32 %0, %1, %2" : "=v"(r) : "v"(lo), "v"(hi));
  return r;
}
__device__ inline float max3f(float a, float b, float c) {
  float r;
  asm("v_max3_f32 %0, %1, %2, %3" : "=v"(r) : "v"(a), "v"(b), "v"(c));
  return r;
}

// XOR-swizzled flat index into a [rows][64] bf16 LDS tile (16B-chunk swizzle).
__device__ inline int swz(int row, int col) {
  return (row << 6) + ((((col >> 3) ^ (row & 7)) << 3) | (col & 7));
}

// ---------------- assemble token streams ----------------
__global__ __launch_bounds__(256) void assemble_kernel(
    const float* __restrict__ cls, const float* __restrict__ pix,
    const float* __restrict__ sur, float* __restrict__ xo, float* __restrict__ xs) {
  int idx = blockIdx.x * 256 + (int)threadIdx.x;
  int total = NB * Nn * Cc;
  if (idx >= total) return;
  int ch = idx % Cc;
  int t  = (idx / Cc) % Nn;
  int b  = idx / (Cc * Nn);
  float vo, vs;
  if (t <= Ss) vo = cls[b * Cc + ch];
  else         vo = pix[(size_t)b * Cc * Ll + (size_t)ch * Ll + (t - Ss - 1)];
  if (t < Ss)  vs = sur[b * Cc + ch];
  else         vs = sur[(size_t)(t - Ss) * NB * Cc + b * Cc + ch];
  xo[idx] = vo;
  xs[idx] = vs;
}

// ---------------- merged fp32 -> bf16 weight convert ----------------
constexpr int CN0 = 3 * 2304 * 768;
constexpr int CN1 = 3 * 768 * 768;
constexpr int CN2 = 3 * 3072 * 768;
constexpr int CN3 = 3 * 768 * 3072;
__global__ __launch_bounds__(256) void cvt4_kernel(
    const float* __restrict__ s0, const float* __restrict__ s1,
    const float* __restrict__ s2, const float* __restrict__ s3,
    u16* __restrict__ dst) {
  int i4 = (blockIdx.x * 256 + (int)threadIdx.x) * 4;
  if (i4 >= CN0 + CN1 + CN2 + CN3) return;
  const float* src; int off;
  if (i4 < CN0)             { src = s0; off = i4; }
  else if (i4 < CN0 + CN1)  { src = s1; off = i4 - CN0; }
  else if (i4 < CN0 + CN1 + CN2) { src = s2; off = i4 - CN0 - CN1; }
  else                      { src = s3; off = i4 - CN0 - CN1 - CN2; }
  float4 v = *(const float4*)(src + off);
  *(ushort4*)(dst + i4) = make_ushort4(f2bf(v.x), f2bf(v.y), f2bf(v.z), f2bf(v.w));
}

// transpose proj_out [768][512] fp32 -> [512][768] bf16
__global__ __launch_bounds__(256) void transpose_po_kernel(
    const float* __restrict__ in, u16* __restrict__ out) {
  int id = blockIdx.x * 256 + (int)threadIdx.x;
  if (id >= 512 * 768) return;
  int nidx = id / 768, k = id - nidx * 768;
  out[id] = f2bf(in[(size_t)k * 512 + nidx]);
}

// ---------------- per-layer V transpose: qkv V -> Vt_g[bh][d][tok VTS] ----
__global__ __launch_bounds__(256) void vtrans_kernel(
    const u16* __restrict__ qkv, u16* __restrict__ vtg) {
  __shared__ u16 tile[64][72];
  int tt = blockIdx.x;   // 0..18 token tiles (tile 18 = zero pad)
  int bh = blockIdx.y;   // 0..23
  int b = bh / Hh, h = bh - b * Hh;
  int tid = (int)threadIdx.x;
  {
    int tl = tid >> 2, c0 = (tid & 3) << 4;
    int tok = tt * 64 + tl;
    int tokc = tok > 1124 ? 1124 : tok;
    const u16* src = qkv + ((size_t)(b * Nn + tokc)) * 2304 + 2 * Cc + h * 64 + c0;
    ushort8v v0 = *(const ushort8v*)src;
    ushort8v v1 = *(const ushort8v*)(src + 8);
    if (tok > 1124) { v0 = (ushort8v)0; v1 = (ushort8v)0; }
    *(ushort8v*)&tile[tl][c0] = v0;
    *(ushort8v*)&tile[tl][c0 + 8] = v1;
  }
  __syncthreads();
  {
    int d = tid >> 2, t0 = (tid & 3) << 4;
    ushort8v o0, o1;
#pragma unroll
    for (int j = 0; j < 8; ++j) { o0[j] = tile[t0 + j][d]; o1[j] = tile[t0 + 8 + j][d]; }
    size_t orow = ((size_t)bh * 64 + d) * VTS + tt * 64 + t0;
    *(ushort8v*)&vtg[orow] = o0;
    *(ushort8v*)&vtg[orow + 8] = o1;
  }
}

// ---------------- layer norm (fp32 in, bf16 out, row gather) ----------------
__global__ __launch_bounds__(256) void ln_kernel(
    const float* __restrict__ X, const float* __restrict__ w, const float* __restrict__ b,
    u16* __restrict__ Y, int rows_per_b, int row_off) {
  int r = blockIdx.x;
  int bb = r / rows_per_b;
  int i  = r % rows_per_b;
  const float* x = X + ((size_t)bb * Nn + row_off + i) * Cc;
  u16* y = Y + (size_t)r * Cc;
  int tid = (int)threadIdx.x;
  float v0 = x[tid], v1 = x[tid + 256], v2 = x[tid + 512];
  float s = v0 + v1 + v2;
  __shared__ float sbuf[4];
  for (int off = 32; off; off >>= 1) s += __shfl_xor(s, off);
  if ((tid & 63) == 0) sbuf[tid >> 6] = s;
  __syncthreads();
  float mean = (sbuf[0] + sbuf[1] + sbuf[2] + sbuf[3]) * (1.0f / Cc);
  float d0 = v0 - mean, d1 = v1 - mean, d2 = v2 - mean;
  float q = d0 * d0 + d1 * d1 + d2 * d2;
  __syncthreads();
  for (int off = 32; off; off >>= 1) q += __shfl_xor(q, off);
  if ((tid & 63) == 0) sbuf[tid >> 6] = q;
  __syncthreads();
  float var = (sbuf[0] + sbuf[1] + sbuf[2] + sbuf[3]) * (1.0f / Cc);
  float inv = rsqrtf(var + 1e-5f);
  y[tid]       = f2bf(d0 * inv * w[tid]       + b[tid]);
  y[tid + 256] = f2bf(d1 * inv * w[tid + 256] + b[tid + 256]);
  y[tid + 512] = f2bf(d2 * inv * w[tid + 512] + b[tid + 512]);
}

// ---------------- bf16 MFMA GEMM, 128x128 tile (qkv / fc) ----------------
__global__ __launch_bounds__(256) void gemm128_kernel(
    const u16* __restrict__ A, const u16* __restrict__ B,
    const float* __restrict__ bias, u16* __restrict__ outb,
    int M, int N, int K, int act) {
  __shared__ __align__(16) u16 Als[128 * 64];
  __shared__ __align__(16) u16 Bls[128 * 64];
  int tid = (int)threadIdx.x;
  int wave = tid >> 6, lane = tid & 63, g = lane >> 4, li = lane & 15;
  int wm = wave >> 1, wn = wave & 1;
  int row0 = blockIdx.y * 128, col0 = blockIdx.x * 128;

  const u16* aptr[4]; const u16* bptr[4]; int dsti[4];
#pragma unroll
  for (int j = 0; j < 4; ++j) {
    int c = tid + j * 256;
    int r = c >> 3, c8 = c & 7;
    dsti[j] = (r << 6) + ((c8 ^ (r & 7)) << 3);
    int ra = row0 + r; if (ra > M - 1) ra = M - 1;
    aptr[j] = A + (size_t)ra * K + (c8 << 3);
    bptr[j] = B + (size_t)(col0 + r) * K + (c8 << 3);
  }

  f32x4 acc[4][4];
#pragma unroll
  for (int mi = 0; mi < 4; ++mi)
#pragma unroll
    for (int ni = 0; ni < 4; ++ni) acc[mi][ni] = (f32x4){0.f, 0.f, 0.f, 0.f};

  for (int k0 = 0; k0 < K; k0 += 64) {
    ushort8v ta[4], tb[4];
#pragma unroll
    for (int j = 0; j < 4; ++j) {
      ta[j] = *(const ushort8v*)(aptr[j] + k0);
      tb[j] = *(const ushort8v*)(bptr[j] + k0);
    }
    __syncthreads();
#pragma unroll
    for (int j = 0; j < 4; ++j) {
      *(ushort8v*)&Als[dsti[j]] = ta[j];
      *(ushort8v*)&Bls[dsti[j]] = tb[j];
    }
    __syncthreads();
#pragma unroll
    for (int kc = 0; kc < 2; ++kc) {
      short8v af[4], bfr[4];
#pragma unroll
      for (int mi = 0; mi < 4; ++mi) {
        int rr = wm * 64 + mi * 16 + li;
        af[mi] = *(const short8v*)&Als[(rr << 6) + (((kc * 4 + g) ^ (rr & 7)) << 3)];
      }
#pragma unroll
      for (int ni = 0; ni < 4; ++ni) {
        int rb = wn * 64 + ni * 16 + li;
        bfr[ni] = *(const short8v*)&Bls[(rb << 6) + (((kc * 4 + g) ^ (rb & 7)) << 3)];
      }
      __builtin_amdgcn_s_setprio(1);
#pragma unroll
      for (int mi = 0; mi < 4; ++mi)
#pragma unroll
        for (int ni = 0; ni < 4; ++ni)
          acc[mi][ni] = __builtin_amdgcn_mfma_f32_16x16x32_bf16(af[mi], bfr[ni], acc[mi][ni], 0, 0, 0);
      __builtin_amdgcn_s_setprio(0);
    }
  }

#pragma unroll
  for (int mi = 0; mi < 4; ++mi) {
#pragma unroll
    for (int r = 0; r < 4; ++r) {
      int m = row0 + wm * 64 + mi * 16 + g * 4 + r;
      if (m >= M) continue;
#pragma unroll
      for (int ni = 0; ni < 4; ++ni) {
        int n = col0 + wn * 64 + ni * 16 + li;
        float v = acc[mi][ni][r];
        if (bias) v += bias[n];
        if (act)  v = v / (1.0f + __expf(-1.702f * v));
        outb[(size_t)m * N + n] = f2bf(v);
      }
    }
  }
}

// ---------------- bf16 MFMA GEMM, 64x128 tile (proj/fc2/head) ---------------
__global__ __launch_bounds__(256) void gemm64_kernel(
    const u16* __restrict__ A0, const u16* __restrict__ A1,
    const u16* __restrict__ B, const float* __restrict__ bias,
    const float* __restrict__ res0, const float* __restrict__ res1,
    float* __restrict__ outf0, float* __restrict__ outf1,
    u16* __restrict__ outb0, u16* __restrict__ outb1,
    int M, int N, int K, int act) {
  __shared__ __align__(16) u16 Als[64 * 64];
  __shared__ __align__(16) u16 Bls[128 * 64];
  int zz = blockIdx.z;
  const u16* A = zz ? A1 : A0;
  const float* res = zz ? res1 : res0;
  float* outf = zz ? outf1 : outf0;
  u16* outb = zz ? outb1 : outb0;
  int tid = (int)threadIdx.x;
  int wave = tid >> 6, lane = tid & 63, g = lane >> 4, li = lane & 15;
  int row0 = blockIdx.y * 64, col0 = blockIdx.x * 128;

  const u16* aptr[2]; int dA[2];
#pragma unroll
  for (int j = 0; j < 2; ++j) {
    int ca = tid + j * 256;
    int r = ca >> 3, c8 = ca & 7;
    dA[j] = (r << 6) + ((c8 ^ (r & 7)) << 3);
    int ra = row0 + r; if (ra > M - 1) ra = M - 1;
    aptr[j] = A + (size_t)ra * K + (c8 << 3);
  }
  const u16* bptr[4]; int dB[4];
#pragma unroll
  for (int j = 0; j < 4; ++j) {
    int cb = tid + j * 256;
    int r = cb >> 3, c8 = cb & 7;
    dB[j] = (r << 6) + ((c8 ^ (r & 7)) << 3);
    bptr[j] = B + (size_t)(col0 + r) * K + (c8 << 3);
  }

  f32x4 acc[4][2];
#pragma unroll
  for (int mi = 0; mi < 4; ++mi)
#pragma unroll
    for (int ni = 0; ni < 2; ++ni) acc[mi][ni] = (f32x4){0.f, 0.f, 0.f, 0.f};

  for (int k0 = 0; k0 < K; k0 += 64) {
    ushort8v ta[2], tb[4];
#pragma unroll
    for (int j = 0; j < 2; ++j) ta[j] = *(const ushort8v*)(aptr[j] + k0);
#pragma unroll
    for (int j = 0; j < 4; ++j) tb[j] = *(const ushort8v*)(bptr[j] + k0);
    __syncthreads();
#pragma unroll
    for (int j = 0; j < 2; ++j) *(ushort8v*)&Als[dA[j]] = ta[j];
#pragma unroll
    for (int j = 0; j < 4; ++j) *(ushort8v*)&Bls[dB[j]] = tb[j];
    __syncthreads();
#pragma unroll
    for (int kc = 0; kc < 2; ++kc) {
      short8v af[4], bfr[2];
#pragma unroll
      for (int mi = 0; mi < 4; ++mi) {
        int rr = mi * 16 + li;
        af[mi] = *(const short8v*)&Als[(rr << 6) + (((kc * 4 + g) ^ (rr & 7)) << 3)];
      }
#pragma unroll
      for (int ni = 0; ni < 2; ++ni) {
        int rb = wave * 32 + ni * 16 + li;
        bfr[ni] = *(const short8v*)&Bls[(rb << 6) + (((kc * 4 + g) ^ (rb & 7)) << 3)];
      }
      __builtin_amdgcn_s_setprio(1);
#pragma unroll
      for (int mi = 0; mi < 4; ++mi)
#pragma unroll
        for (int ni = 0; ni < 2; ++ni)
          acc[mi][ni] = __builtin_amdgcn_mfma_f32_16x16x32_bf16(af[mi], bfr[ni], acc[mi][ni], 0, 0, 0);
      __builtin_amdgcn_s_setprio(0);
    }
  }

#pragma unroll
  for (int mi = 0; mi < 4; ++mi) {
#pragma unroll
    for (int r = 0; r < 4; ++r) {
      int m = row0 + mi * 16 + g * 4 + r;
      if (m >= M) continue;
#pragma unroll
      for (int ni = 0; ni < 2; ++ni) {
        int n = col0 + wave * 32 + ni * 16 + li;
        float v = acc[mi][ni][r];
        if (bias) v += bias[n];
        if (act)  v = v / (1.0f + __expf(-1.702f * v));
        if (res)  v += res[(size_t)m * N + n];
        if (outf) outf[(size_t)m * N + n] = v;
        else      outb[(size_t)m * N + n] = f2bf(v);
      }
    }
  }
}

// ---------------- swapped-QK^T flash attention, 2-way key-split -------------
// Grid 1824 = 8 XCD chunks x 228. virt -> (gidh, qt); half = gidh&1,
// gid = gidh>>1 (both halves of a (z,bh) share an XCD -> L2 locality).
// Per wave: 16 queries (q = li). K rows at LDS row rho(k). Vt key-identity.
// half0: kt 0..8, half1: kt 9..NT-1. Emits fp32 unnormalized O-partials +
// (m,l) (log2 domain); combined by attn_combine. ALWAYS-rescale softmax.
__global__ __launch_bounds__(256) void attn_kernel(
    const u16* __restrict__ qkv, const u16* __restrict__ vtg,
    const float* __restrict__ abias,
    float* __restrict__ opart, float* __restrict__ mlp) {
  __shared__ __align__(16) u16 Klds[64 * 64];
  __shared__ __align__(16) u16 Vt[64 * 64];      // [d][key] swizzled
  int id = (int)blockIdx.x;
  int virt = (id & 7) * 228 + (id >> 3);   // 1824 = 8*228, bijective
  int gidh = virt / 19;
  int qt   = virt - gidh * 19;
  int half = gidh & 1;
  int gid  = gidh >> 1;
  int z    = gid / 24;                      // pass: 0=ORI, 1=SUR
  int bh   = gid - z * 24;
  int b = bh / Hh, h = bh - b * Hh;
  int tid = (int)threadIdx.x;
  int wave = tid >> 6, lane = tid & 63, g = lane >> 4, li = lane & 15;
  bool sosq = qt >= 17;

  int qbase = sosq ? (qt - 17) * 64 + wave * 16 : Ss + qt * 64 + wave * 16;
  int qtok = qbase + li;
  int qcap = sosq ? 99 : 1124;
  if (qtok > qcap) qtok = qcap;
  int qoff = z ? 2 * Cc + h * 64 : h * 64;
  int koff = z ? 2 * Cc + h * 64 : Cc + h * 64;

  // B-fragment: lane holds its q row (q = li), pre-scaled by 0.125*log2e
  short8v qf[2];
  {
    const u16* qp = qkv + ((size_t)b * Nn + qtok) * 2304 + qoff;
#pragma unroll
    for (int kc = 0; kc < 2; ++kc) {
      ushort8v a = *(const ushort8v*)(qp + kc * 32 + g * 8);
      u32x4 w;
#pragma unroll
      for (int jj = 0; jj < 4; ++jj)
        w[jj] = cvtpk(bf2f(a[2 * jj]) * QS, bf2f(a[2 * jj + 1]) * QS);
      qf[kc] = __builtin_bit_cast(short8v, w);
    }
  }

  int skey = tid >> 2;           // K: key row staged; Vt: d row staged
  int sd0  = (tid & 3) << 4;
  // rho permutation (K side ONLY): LDS row for staged key `skey`
  int prow = 16 * (2 * (skey >> 5) + ((skey >> 2) & 1)) + 4 * ((skey >> 3) & 3) + (skey & 3);
  int kK0 = swz(prow, sd0), kK1 = swz(prow, sd0 + 8);
  int vI0 = swz(skey, sd0), vI1 = swz(skey, sd0 + 8);
  const u16* kbase = qkv + (size_t)b * Nn * 2304 + koff + sd0;
  const u16* vbase = vtg + ((size_t)bh * 64 + skey) * VTS + sd0;

  const int KOFF[4] = {0, 4, 32, 36};   // within-tile key base per nt (+8g+r)

  f32x4 oacc[4];
#pragma unroll
  for (int dt = 0; dt < 4; ++dt) oacc[dt] = (f32x4){0.f, 0.f, 0.f, 0.f};
  float mrow = -1e30f, lrow = 0.f;

  int NT = sosq ? 18 : 17;
  int kt0 = half * 9;
  int kt1 = half ? NT : 9;
  for (int kt = kt0; kt < kt1; ++kt) {
    int t0 = sosq ? (kt == 0 ? (qt - 17) * 64 : 64 * kt + 32) : 96 + 64 * kt;
    __syncthreads();
    {
      int ktok = t0 + skey; if (ktok > 1124) ktok = 1124;
      const u16* kp = kbase + (size_t)ktok * 2304;
      ushort8v k0v = *(const ushort8v*)kp;
      ushort8v k1v = *(const ushort8v*)(kp + 8);
      const u16* vp = vbase + t0;
      ushort8v v0 = *(const ushort8v*)vp;
      ushort8v v1 = *(const ushort8v*)(vp + 8);
      *(ushort8v*)&Klds[kK0] = k0v;
      *(ushort8v*)&Klds[kK1] = k1v;
      *(ushort8v*)&Vt[vI0] = v0;
      *(ushort8v*)&Vt[vI1] = v1;
    }
    __syncthreads();

    // S^T = K Q^T  (A = K rows from rho-permuted LDS, B = Q frag)
    f32x4 sacc[4];
#pragma unroll
    for (int nt = 0; nt < 4; ++nt) sacc[nt] = (f32x4){0.f, 0.f, 0.f, 0.f};
    __builtin_amdgcn_s_setprio(1);
#pragma unroll
    for (int kc = 0; kc < 2; ++kc) {
#pragma unroll
      for (int nt = 0; nt < 4; ++nt) {
        short8v kb = *(const short8v*)&Klds[swz(nt * 16 + li, kc * 32 + g * 8)];
        sacc[nt] = __builtin_amdgcn_mfma_f32_16x16x32_bf16(kb, qf[kc], sacc[nt], 0, 0, 0);
      }
    }
    __builtin_amdgcn_s_setprio(0);

    // masking / bias; lane's (nt,r) is key t0 + KOFF[nt] + 8g + r
    int tg = t0 + 8 * g;
    if (!sosq) {
      if (kt == 0) {
#pragma unroll
        for (int nt = 0; nt < 4; ++nt)
#pragma unroll
          for (int r = 0; r < 4; ++r)
            if (tg + KOFF[nt] + r < 100) sacc[nt][r] = -1e30f;
      } else if (kt == 16) {
#pragma unroll
        for (int nt = 0; nt < 4; ++nt)
#pragma unroll
          for (int r = 0; r < 4; ++r)
            if (tg + KOFF[nt] + r > 1124) sacc[nt][r] = -1e30f;
      }
    } else {
      if (kt == 0) {
#pragma unroll
        for (int nt = 0; nt < 4; ++nt)
#pragma unroll
          for (int r = 0; r < 4; ++r)
            if (tg + KOFF[nt] + r != qtok) sacc[nt][r] = -1e30f;
      } else if (z == 0) {
        const float* bp = abias + ((size_t)b * Ss + qtok) * Ll;
#pragma unroll
        for (int nt = 0; nt < 4; ++nt)
#pragma unroll
          for (int r = 0; r < 4; ++r) {
            int tok = tg + KOFF[nt] + r;
            int bi = tok - 101; bi = bi < 0 ? 0 : bi; bi = bi > 1023 ? 1023 : bi;
            float bv = bp[bi];
            bool bad = (tok < 101) | (tok > 1124);
            sacc[nt][r] = bad ? -1e30f : fmaf(bv, LOG2E, sacc[nt][r]);
          }
      } else {
#pragma unroll
        for (int nt = 0; nt < 4; ++nt)
#pragma unroll
          for (int r = 0; r < 4; ++r) {
            int tok = tg + KOFF[nt] + r;
            if ((tok < 101) | (tok > 1124)) sacc[nt][r] = -1e30f;
          }
      }
    }

    // online softmax (log2 domain), ALWAYS-rescale (dominant P == 1.0 exact)
    float rmax = max3f(sacc[0][0], sacc[0][1], sacc[0][2]);
    rmax = max3f(rmax, sacc[0][3], sacc[1][0]);
    rmax = max3f(rmax, sacc[1][1], sacc[1][2]);
    rmax = max3f(rmax, sacc[1][3], sacc[2][0]);
    rmax = max3f(rmax, sacc[2][1], sacc[2][2]);
    rmax = max3f(rmax, sacc[2][3], sacc[3][0]);
    rmax = max3f(rmax, sacc[3][1], sacc[3][2]);
    rmax = fmaxf(rmax, sacc[3][3]);
    rmax = fmaxf(rmax, __shfl_xor(rmax, 16));
    rmax = fmaxf(rmax, __shfl_xor(rmax, 32));
    float mnew = fmaxf(mrow, rmax);
    float fac = __builtin_amdgcn_exp2f(mrow - mnew);
    mrow = mnew;
    float psum = 0.f;
#pragma unroll
    for (int nt = 0; nt < 4; ++nt)
#pragma unroll
      for (int r = 0; r < 4; ++r) {
        float e = __builtin_amdgcn_exp2f(sacc[nt][r] - mnew);
        sacc[nt][r] = e;
        psum += e;
      }
    psum += __shfl_xor(psum, 16);
    psum += __shfl_xor(psum, 32);
    lrow = lrow * fac + psum;
#pragma unroll
    for (int dt = 0; dt < 4; ++dt) oacc[dt] *= fac;

    // O^T += V^T P^T : B operand is the lane's own packed P values
    __builtin_amdgcn_s_setprio(1);
#pragma unroll
    for (int kcp = 0; kcp < 2; ++kcp) {
      u32x4 pwv;
#pragma unroll
      for (int w = 0; w < 4; ++w) {
        int nt = 2 * kcp + (w >> 1);
        int r0 = (w & 1) * 2;
        pwv[w] = cvtpk(sacc[nt][r0], sacc[nt][r0 + 1]);
      }
      short8v pb = __builtin_bit_cast(short8v, pwv);
#pragma unroll
      for (int dt = 0; dt < 4; ++dt) {
        short8v va = *(const short8v*)&Vt[swz(dt * 16 + li, kcp * 32 + g * 8)];
        oacc[dt] = __builtin_amdgcn_mfma_f32_16x16x32_bf16(va, pb, oacc[dt], 0, 0, 0);
      }
    }
    __builtin_amdgcn_s_setprio(0);
  }

  // epilogue: unnormalized fp32 partials + (m,l) once per q (g==0 lane)
  int tok = qbase + li;
  if (tok <= qcap) {
    int hp = half * 2 + z;
    float* op = opart + ((size_t)hp * NB * Nn + (size_t)b * Nn + tok) * Cc + h * 64 + g * 4;
#pragma unroll
    for (int dt = 0; dt < 4; ++dt)
      *(float4*)(op + dt * 16) = make_float4(oacc[dt][0], oacc[dt][1], oacc[dt][2], oacc[dt][3]);
    if (g == 0) {
      size_t mb = (((size_t)hp * 24 + bh) * Nn + tok) * 2;
      mlp[mb] = mrow;
      mlp[mb + 1] = lrow;
    }
  }
}

// ---------------- combine key-halves (log2-domain flash merge) --------------
__global__ __launch_bounds__(256) void attn_combine_kernel(
    const float* __restrict__ opart, const float* __restrict__ mlp,
    u16* __restrict__ ao, u16* __restrict__ as_) {
  int blk = blockIdx.x;            // pass*(NB*Nn) + row
  int pass = blk / (NB * Nn);
  int row = blk - pass * (NB * Nn);
  int b = row / Nn, i = row - b * Nn;
  u16* outp = pass ? as_ : ao;
  int tid = (int)threadIdx.x;
#pragma unroll
  for (int e = 0; e < 3; ++e) {
    int c = tid + e * 256;
    int h = c >> 6;
    int bh = b * Hh + h;
    size_t m0i = (((size_t)(0 * 2 + pass) * 24 + bh) * Nn + i) * 2;
    size_t m1i = (((size_t)(1 * 2 + pass) * 24 + bh) * Nn + i) * 2;
    float m0 = mlp[m0i], l0 = mlp[m0i + 1];
    float m1 = mlp[m1i], l1 = mlp[m1i + 1];
    float M = fmaxf(m0, m1);
    float w0 = __builtin_amdgcn_exp2f(m0 - M);
    float w1 = __builtin_amdgcn_exp2f(m1 - M);
    float L = l0 * w0 + l1 * w1;
    float v0 = opart[((size_t)(0 * 2 + pass) * NB * Nn + row) * Cc + c];
    float v1 = opart[((size_t)(1 * 2 + pass) * NB * Nn + row) * Cc + c];
    outp[(size_t)row * Cc + c] = f2bf((v0 * w0 + v1 * w1) / L);
  }
}

// ---------------- l2norm heads ----------------
__global__ __launch_bounds__(256) void l2norm_sos_kernel(
    const float* __restrict__ Xp, float* __restrict__ out) {
  int r = blockIdx.x;
  int tid = (int)threadIdx.x;
  const float* x = Xp + (size_t)r * 512;
  float v0 = x[tid], v1 = x[tid + 256];
  float s = v0 * v0 + v1 * v1;
  __shared__ float sbuf[4];
  for (int off = 32; off; off >>= 1) s += __shfl_xor(s, off);
  if ((tid & 63) == 0) sbuf[tid >> 6] = s;
  __syncthreads();
  float tot = sbuf[0] + sbuf[1] + sbuf[2] + sbuf[3];
  float inv = 1.0f / fmaxf(sqrtf(tot), 1e-12f);
  out[(size_t)r * 512 + tid]       = v0 * inv;
  out[(size_t)r * 512 + tid + 256] = v1 * inv;
}

__global__ __launch_bounds__(256) void l2norm_img_kernel(
    const float* __restrict__ Xp, float* __restrict__ out) {
  int r = blockIdx.x;           // b*1025 + ti
  int b = r / 1025, ti = r % 1025;
  int tid = (int)threadIdx.x;
  const float* x = Xp + (size_t)r * 512;
  float v0 = x[tid], v1 = x[tid + 256];
  float s = v0 * v0 + v1 * v1;
  __shared__ float sbuf[4];
  for (int off = 32; off; off >>= 1) s += __shfl_xor(s, off);
  if ((tid & 63) == 0) sbuf[tid >> 6] = s;
  __syncthreads();
  float tot = sbuf[0] + sbuf[1] + sbuf[2] + sbuf[3];
  if (ti == 0) return;          // first surgery row (token S) is discarded
  float inv = 1.0f / fmaxf(sqrtf(tot), 1e-12f);
  float* o = out + (size_t)b * 512 * 1024 + (ti - 1);
  o[(size_t)tid * 1024]         = v0 * inv;
  o[(size_t)(tid + 256) * 1024] = v1 * inv;
}

extern "C" void kernel_launch(void* const* d_in, const int* in_sizes, int n_in,
                              void* d_out, int out_size, void* d_ws, size_t ws_size,
                              hipStream_t stream) {
  const float* cls      = (const float*)d_in[0];
  const float* pix      = (const float*)d_in[1];
  const float* sur      = (const float*)d_in[2];
  const float* abias    = (const float*)d_in[3];
  const float* qkv_w    = (const float*)d_in[4];
  const float* qkv_b    = (const float*)d_in[5];
  const float* proj_w   = (const float*)d_in[6];
  const float* proj_b   = (const float*)d_in[7];
  const float* ln1_w    = (const float*)d_in[8];
  const float* ln1_b    = (const float*)d_in[9];
  const float* ln2_w    = (const float*)d_in[10];
  const float* ln2_b    = (const float*)d_in[11];
  const float* fc_w     = (const float*)d_in[12];
  const float* fc_b     = (const float*)d_in[13];
  const float* fc2_w    = (const float*)d_in[14];
  const float* fc2_b    = (const float*)d_in[15];
  const float* lnp_w    = (const float*)d_in[16];
  const float* lnp_b    = (const float*)d_in[17];
  const float* proj_o   = (const float*)d_in[18];
  float* out = (float*)d_out;

  const size_t SZ = (size_t)NB * Nn * Cc;        // 1,728,000
  float* xo    = (float*)d_ws;
  float* xs    = xo + SZ;
  float* opart = xs + SZ;                         // 4*2250*768 f32
  float* mlp   = opart + (size_t)4 * 2250 * 768;  // 4*24*1125*2 f32
  float* head_pj = opart;                         // reused at head phase
  u16* tln_bf = (u16*)(mlp + (size_t)4 * 24 * 1125 * 2);
  u16* act_bf = tln_bf + (size_t)2250 * 768;      // 2250*3072
  u16* ao_bf  = act_bf + (size_t)2250 * 3072;     // 2250*768
  u16* as_bf  = ao_bf + (size_t)2250 * 768;       // 2250*768
  u16* wq_bf  = as_bf + (size_t)2250 * 768;       // 3*2304*768
  u16* wp_bf  = wq_bf + (size_t)CN0;              // 3*768*768
  u16* wf_bf  = wp_bf + (size_t)CN1;              // 3*3072*768
  u16* w2_bf  = wf_bf + (size_t)CN2;              // 3*768*3072
  u16* wo_bf  = w2_bf + (size_t)CN3;              // 512*768
  u16* vtg    = wo_bf + (size_t)512 * 768;        // 24*64*VTS

  assemble_kernel<<<6750, 256, 0, stream>>>(cls, pix, sur, xo, xs);
  cvt4_kernel<<<20736, 256, 0, stream>>>(qkv_w, proj_w, fc_w, fc2_w, wq_bf);
  transpose_po_kernel<<<1536, 256, 0, stream>>>(proj_o, wo_bf);

  for (int l = 0; l < 3; ++l) {
    ln_kernel<<<2250, 256, 0, stream>>>(xo, ln1_w + l * 768, ln1_b + l * 768, tln_bf, Nn, 0);
    gemm128_kernel<<<dim3(18, 18), 256, 0, stream>>>(
        tln_bf, wq_bf + (size_t)l * 2304 * 768, qkv_b + l * 2304,
        act_bf, 2250, 2304, 768, 0);
    vtrans_kernel<<<dim3(19, 24), 256, 0, stream>>>(act_bf, vtg);
    attn_kernel<<<1824, 256, 0, stream>>>(act_bf, vtg, abias, opart, mlp);
    attn_combine_kernel<<<4500, 256, 0, stream>>>(opart, mlp, ao_bf, as_bf);
    gemm64_kernel<<<dim3(6, 36, 2), 256, 0, stream>>>(
        ao_bf, as_bf, wp_bf + (size_t)l * 768 * 768, proj_b + l * 768,
        xo, xs, xo, xs, nullptr, nullptr, 2250, 768, 768, 0);
    ln_kernel<<<2250, 256, 0, stream>>>(xo, ln2_w + l * 768, ln2_b + l * 768, tln_bf, Nn, 0);
    gemm128_kernel<<<dim3(24, 18), 256, 0, stream>>>(
        tln_bf, wf_bf + (size_t)l * 3072 * 768, fc_b + l * 3072,
        act_bf, 2250, 3072, 768, 1);
    gemm64_kernel<<<dim3(6, 36, 1), 256, 0, stream>>>(
        act_bf, act_bf, w2_bf + (size_t)l * 768 * 3072, fc2_b + l * 768,
        xo, xo, xo, xo, nullptr, nullptr, 2250, 768, 3072, 0);
  }

  // heads
  ln_kernel<<<200, 256, 0, stream>>>(xo, lnp_w, lnp_b, tln_bf, 100, 0);
  ln_kernel<<<2050, 256, 0, stream>>>(xs, lnp_w, lnp_b, tln_bf + 200 * 768, 1025, 100);
  gemm64_kernel<<<dim3(4, 36, 1), 256, 0, stream>>>(
      tln_bf, tln_bf, wo_bf, nullptr,
      nullptr, nullptr, head_pj, head_pj, nullptr, nullptr, 2250, 512, 768, 0);
  l2norm_sos_kernel<<<200, 256, 0, stream>>>(head_pj, out);
  l2norm_img_kernel<<<2050, 256, 0, stream>>>(head_pj + 200 * 512, out + 102400);
}